// Round 1
// baseline (1090.404 us; speedup 1.0000x reference)
//
#include <hip/hip_runtime.h>

#define NNODES 100000
#define NMP 3
#define NEDGES 1000000
#define D 64

// ---------------- degree accumulation: deg[mp][c] += ew[mp][e] ----------------
__global__ __launch_bounds__(256) void deg_kernel(const int* __restrict__ ei,
                                                  const float* __restrict__ ew,
                                                  float* __restrict__ deg) {
    int e = blockIdx.x * 256 + threadIdx.x;
    int mp = blockIdx.y;
    if (e >= NEDGES) return;
    int c = ei[(mp * 2 + 1) * NEDGES + e];
    atomicAdd(&deg[mp * NNODES + c], ew[mp * NEDGES + e]);
}

// ---------------- dinv = deg>0 ? rsqrt(deg) : 0 (in place) ----------------
__global__ __launch_bounds__(256) void dinv_kernel(float* __restrict__ deg) {
    int i = blockIdx.x * 256 + threadIdx.x;
    if (i >= NMP * NNODES) return;
    float d = deg[i];
    deg[i] = (d > 0.0f) ? rsqrtf(d) : 0.0f;
}

// ---------------- h[mp] = x @ W[mp]  (fp32, vector ALU; K=64, N=64) ----------------
// 256 threads = 4 rows x 64 cols per block. W[mp] (16 KB) + 4 x-rows staged in LDS.
__global__ __launch_bounds__(256) void gemm_kernel(const float* __restrict__ x,
                                                   const float* __restrict__ W,
                                                   float* __restrict__ h) {
    __shared__ float Wl[D * D];
    __shared__ float xs[4][D];
    const int mp = blockIdx.y;
    const int tid = threadIdx.x;
    for (int i = tid; i < D * D; i += 256) Wl[i] = W[mp * D * D + i];
    const int ri = tid >> 6;          // 0..3 row within block
    const int j  = tid & 63;          // output column
    const int r  = blockIdx.x * 4 + ri;
    xs[ri][j] = (r < NNODES) ? x[r * D + j] : 0.0f;
    __syncthreads();
    if (r < NNODES) {
        float acc = 0.0f;
#pragma unroll
        for (int k = 0; k < D; ++k) acc += xs[ri][k] * Wl[k * D + j];
        h[((size_t)mp * NNODES + r) * D + j] = acc;
    }
}

// ---------------- scatter: out[mp][c][j] += dinv[r]*ew*dinv[c] * h[mp][r][j] ----------------
// one wave (64 lanes) per edge; lane j handles feature j.
__global__ __launch_bounds__(256) void scatter_kernel(const int* __restrict__ ei,
                                                      const float* __restrict__ ew,
                                                      const float* __restrict__ dinv,
                                                      const float* __restrict__ h,
                                                      float* __restrict__ out) {
    const int mp   = blockIdx.y;
    const int edge = blockIdx.x * 4 + (threadIdx.x >> 6);
    const int lane = threadIdx.x & 63;
    if (edge >= NEDGES) return;
    const int r = ei[(mp * 2 + 0) * NEDGES + edge];
    const int c = ei[(mp * 2 + 1) * NEDGES + edge];
    const float norm = dinv[mp * NNODES + r] * ew[mp * NEDGES + edge] * dinv[mp * NNODES + c];
    const float val = h[((size_t)mp * NNODES + r) * D + lane] * norm;
    atomicAdd(&out[((size_t)mp * NNODES + c) * D + lane], val);
}

// ---------------- relu in place (float4) ----------------
__global__ __launch_bounds__(256) void relu_kernel(float4* __restrict__ out, int n4) {
    int i = blockIdx.x * 256 + threadIdx.x;
    if (i >= n4) return;
    float4 v = out[i];
    v.x = fmaxf(v.x, 0.0f);
    v.y = fmaxf(v.y, 0.0f);
    v.z = fmaxf(v.z, 0.0f);
    v.w = fmaxf(v.w, 0.0f);
    out[i] = v;
}

extern "C" void kernel_launch(void* const* d_in, const int* in_sizes, int n_in,
                              void* d_out, int out_size, void* d_ws, size_t ws_size,
                              hipStream_t stream) {
    const float* x  = (const float*)d_in[0];   // [N, 64]
    const float* W  = (const float*)d_in[1];   // [3, 64, 64]
    const int*   ei = (const int*)d_in[2];     // [3, 2, E]
    const float* ew = (const float*)d_in[3];   // [3, E]
    float* out = (float*)d_out;                // [3, N, 64]

    float* deg = (float*)d_ws;                 // 3*N floats (deg -> dinv in place)
    float* h   = deg + (size_t)NMP * NNODES;   // 3*N*64 floats

    const size_t out_bytes = sizeof(float) * (size_t)NMP * NNODES * D;
    const size_t deg_bytes = sizeof(float) * (size_t)NMP * NNODES;

    hipMemsetAsync(d_out, 0, out_bytes, stream);
    hipMemsetAsync(deg, 0, deg_bytes, stream);

    deg_kernel<<<dim3((NEDGES + 255) / 256, NMP), 256, 0, stream>>>(ei, ew, deg);
    dinv_kernel<<<(NMP * NNODES + 255) / 256, 256, 0, stream>>>(deg);
    gemm_kernel<<<dim3((NNODES + 3) / 4, NMP), 256, 0, stream>>>(x, W, h);
    scatter_kernel<<<dim3((NEDGES + 3) / 4, NMP), 256, 0, stream>>>(ei, ew, deg, h, out);

    const int n4 = NMP * NNODES * D / 4;
    relu_kernel<<<(n4 + 255) / 256, 256, 0, stream>>>((float4*)out, n4);
}

// Round 2
// 869.836 us; speedup vs baseline: 1.2536x; 1.2536x over previous
//
#include <hip/hip_runtime.h>

#define NNODES 100000
#define NMP 3
#define NEDGES 1000000
#define D 64
#define NTOT (NMP * NNODES)          // 300000 flat (mp,node) slots
#define SCAN_BLOCKS ((NTOT + 1023) / 1024)   // 293

// ---------------- deg[c] += ew ; cnt[c] += 1 ----------------
__global__ __launch_bounds__(256) void deg_cnt_kernel(const int* __restrict__ ei,
                                                      const float* __restrict__ ew,
                                                      float* __restrict__ deg,
                                                      int* __restrict__ cnt) {
    int e = blockIdx.x * 256 + threadIdx.x;
    int mp = blockIdx.y;
    if (e >= NEDGES) return;
    int c = ei[(mp * 2 + 1) * NEDGES + e];
    atomicAdd(&deg[mp * NNODES + c], ew[mp * NEDGES + e]);
    atomicAdd(&cnt[mp * NNODES + c], 1);
}

// ---------------- dinv = deg>0 ? rsqrt(deg) : 0 (in place) ----------------
__global__ __launch_bounds__(256) void dinv_kernel(float* __restrict__ deg) {
    int i = blockIdx.x * 256 + threadIdx.x;
    if (i >= NTOT) return;
    float d = deg[i];
    deg[i] = (d > 0.0f) ? rsqrtf(d) : 0.0f;
}

// ---------------- scan stage 1: per-1024-element block sums ----------------
__global__ __launch_bounds__(256) void scan1_kernel(const int* __restrict__ cnt,
                                                    int* __restrict__ blockSums) {
    int t = threadIdx.x, b = blockIdx.x;
    int i4 = b * 256 + t;
    int4 v = (i4 < NTOT / 4) ? ((const int4*)cnt)[i4] : make_int4(0, 0, 0, 0);
    int s = v.x + v.y + v.z + v.w;
    for (int off = 32; off; off >>= 1) s += __shfl_down(s, off);
    __shared__ int red[4];
    if ((t & 63) == 0) red[t >> 6] = s;
    __syncthreads();
    if (t == 0) blockSums[b] = red[0] + red[1] + red[2] + red[3];
}

// ---------------- scan stage 2: exclusive scan of block sums (1 block) ----------------
__global__ __launch_bounds__(512) void scan2_kernel(const int* __restrict__ blockSums,
                                                    int* __restrict__ blockOffs,
                                                    int* __restrict__ offsetsEnd) {
    __shared__ int sh[512];
    int t = threadIdx.x;
    int v = (t < SCAN_BLOCKS) ? blockSums[t] : 0;
    sh[t] = v;
    __syncthreads();
    for (int d = 1; d < 512; d <<= 1) {
        int add = (t >= d) ? sh[t - d] : 0;
        __syncthreads();
        sh[t] += add;
        __syncthreads();
    }
    if (t < SCAN_BLOCKS) blockOffs[t] = sh[t] - v;   // exclusive
    if (t == 511) *offsetsEnd = sh[511];             // total (= 3*NEDGES)
}

// ---------------- scan stage 3: full offsets + cursor init ----------------
__global__ __launch_bounds__(256) void scan3_kernel(const int* __restrict__ cnt,
                                                    const int* __restrict__ blockOffs,
                                                    int* __restrict__ offsets,
                                                    int* __restrict__ cursor) {
    int t = threadIdx.x, b = blockIdx.x;
    int i4 = b * 256 + t;
    int4 v = (i4 < NTOT / 4) ? ((const int4*)cnt)[i4] : make_int4(0, 0, 0, 0);
    int s = v.x + v.y + v.z + v.w;
    __shared__ int sh[256];
    sh[t] = s;
    __syncthreads();
    for (int d = 1; d < 256; d <<= 1) {
        int add = (t >= d) ? sh[t - d] : 0;
        __syncthreads();
        sh[t] += add;
        __syncthreads();
    }
    int excl = sh[t] - s + blockOffs[b];
    if (i4 < NTOT / 4) {
        int o0 = excl, o1 = o0 + v.x, o2 = o1 + v.y, o3 = o2 + v.z;
        int4 o = make_int4(o0, o1, o2, o3);
        ((int4*)offsets)[i4] = o;
        ((int4*)cursor)[i4] = o;
    }
}

// ---------------- h[mp] = x @ W[mp]  (32 rows/block, 8 outputs/thread) ----------------
__global__ __launch_bounds__(256) void gemm_kernel(const float* __restrict__ x,
                                                   const float* __restrict__ W,
                                                   float* __restrict__ h) {
    __shared__ float Wl[D * D];
    __shared__ float xs[32][D];
    const int mp = blockIdx.y;
    const int tid = threadIdx.x;
    const float4* W4 = (const float4*)(W + mp * D * D);
    float4* Wl4 = (float4*)Wl;
#pragma unroll
    for (int i = 0; i < 4; ++i) Wl4[i * 256 + tid] = W4[i * 256 + tid];
    const size_t rowbase = (size_t)blockIdx.x * 32;   // NNODES = 32*3125, no remainder
    const float4* x4 = (const float4*)(x + rowbase * D);
    float4* xs4 = (float4*)xs;
#pragma unroll
    for (int i = 0; i < 2; ++i) xs4[i * 256 + tid] = x4[i * 256 + tid];
    __syncthreads();
    const int j = tid & 63;
    const int g = tid >> 6;        // 0..3, rows g*8 .. g*8+7
    float acc[8] = {0, 0, 0, 0, 0, 0, 0, 0};
#pragma unroll
    for (int k = 0; k < D; ++k) {
        float wv = Wl[k * D + j];
#pragma unroll
        for (int m = 0; m < 8; ++m) acc[m] += xs[g * 8 + m][k] * wv;
    }
#pragma unroll
    for (int m = 0; m < 8; ++m)
        h[((size_t)mp * NNODES + rowbase + g * 8 + m) * D + j] = acc[m];
}

// ---------------- placement: bucket {rflat, norm} pairs by destination ----------------
__global__ __launch_bounds__(256) void place_kernel(const int* __restrict__ ei,
                                                    const float* __restrict__ ew,
                                                    const float* __restrict__ dinv,
                                                    int* __restrict__ cursor,
                                                    int2* __restrict__ pairs) {
    int e = blockIdx.x * 256 + threadIdx.x;
    int mp = blockIdx.y;
    if (e >= NEDGES) return;
    int r = ei[(mp * 2 + 0) * NEDGES + e];
    int c = ei[(mp * 2 + 1) * NEDGES + e];
    int rflat = mp * NNODES + r;
    int cflat = mp * NNODES + c;
    float norm = dinv[rflat] * ew[mp * NEDGES + e] * dinv[cflat];
    int pos = atomicAdd(&cursor[cflat], 1);
    int2 p;
    p.x = rflat;
    p.y = __float_as_int(norm);
    pairs[pos] = p;
}

// ---------------- gather: one wave per (mp,node); fused ReLU; writes all of out ----------------
__global__ __launch_bounds__(256) void gather_kernel(const int* __restrict__ offsets,
                                                     const int2* __restrict__ pairs,
                                                     const float* __restrict__ h,
                                                     float* __restrict__ out) {
    int w = blockIdx.x * 4 + (threadIdx.x >> 6);
    int lane = threadIdx.x & 63;
    if (w >= NTOT) return;
    int start = offsets[w], end = offsets[w + 1];
    float acc = 0.0f;
    for (int p = start; p < end; ++p) {
        int2 pr = pairs[p];
        acc += __int_as_float(pr.y) * h[(size_t)pr.x * D + lane];
    }
    out[(size_t)w * D + lane] = fmaxf(acc, 0.0f);
}

extern "C" void kernel_launch(void* const* d_in, const int* in_sizes, int n_in,
                              void* d_out, int out_size, void* d_ws, size_t ws_size,
                              hipStream_t stream) {
    const float* x  = (const float*)d_in[0];   // [N, 64]
    const float* W  = (const float*)d_in[1];   // [3, 64, 64]
    const int*   ei = (const int*)d_in[2];     // [3, 2, E]
    const float* ew = (const float*)d_in[3];   // [3, E]
    float* out = (float*)d_out;                // [3, N, 64]

    // workspace layout (element offsets into float/int array; all 16B-aligned where needed)
    float* wsf = (float*)d_ws;
    int*   wsi = (int*)d_ws;
    float* deg       = wsf;                    // [0, 300000)          deg -> dinv in place
    int*   cnt       = wsi + 300000;           // [300000, 600000)
    int*   offsets   = wsi + 600000;           // [600000, 900001)
    int*   cursor    = wsi + 900004;           // [900004, 1200004)
    int*   blockSums = wsi + 1200004;          // 293
    int*   blockOffs = wsi + 1200304;          // 293
    int2*  pairs     = (int2*)(wsi + 1200600); // 3,000,000 pairs (24 MB), 8B-aligned
    float* h         = wsf + 7200600;          // 19,200,000 floats (76.8 MB), 16B-aligned

    // zero deg+cnt (contiguous 2.4 MB)
    hipMemsetAsync(deg, 0, sizeof(int) * 600000, stream);

    dim3 egrid((NEDGES + 255) / 256, NMP);
    deg_cnt_kernel<<<egrid, 256, 0, stream>>>(ei, ew, deg, cnt);
    dinv_kernel<<<(NTOT + 255) / 256, 256, 0, stream>>>(deg);
    scan1_kernel<<<SCAN_BLOCKS, 256, 0, stream>>>(cnt, blockSums);
    scan2_kernel<<<1, 512, 0, stream>>>(blockSums, blockOffs, &offsets[NTOT]);
    scan3_kernel<<<SCAN_BLOCKS, 256, 0, stream>>>(cnt, blockOffs, offsets, cursor);
    gemm_kernel<<<dim3(NNODES / 32, NMP), 256, 0, stream>>>(x, W, h);
    place_kernel<<<egrid, 256, 0, stream>>>(ei, ew, deg, cursor, pairs);
    gather_kernel<<<(NTOT + 3) / 4, 256, 0, stream>>>(offsets, pairs, h, out);
}

// Round 3
// 550.094 us; speedup vs baseline: 1.9822x; 1.5812x over previous
//
#include <hip/hip_runtime.h>

#define NNODES 100000
#define NMP 3
#define NEDGES 1000000
#define D 64
#define NTOT (NMP * NNODES)                   // 300000
#define SCAN_BLOCKS ((NTOT / 4 + 255) / 256)  // 293

typedef __attribute__((ext_vector_type(8))) short bf16x8;
typedef __attribute__((ext_vector_type(4))) float floatx4;

__device__ __forceinline__ unsigned short f2bf(float f) {
    unsigned u = __float_as_uint(f);
    u = (u + 0x7FFFu + ((u >> 16) & 1u)) >> 16;   // RNE
    return (unsigned short)u;
}

// ---------------- pass over edges: one packed u64 atomic: cnt<<52 | ew in 12.40 fixed ----------------
__global__ __launch_bounds__(256) void deg_cnt_kernel(const int* __restrict__ ei,
                                                      const float* __restrict__ ew,
                                                      unsigned long long* __restrict__ degcnt) {
    int e = blockIdx.x * 256 + threadIdx.x;
    int mp = blockIdx.y;
    if (e >= NEDGES) return;
    int c = ei[(mp * 2 + 1) * NEDGES + e];
    float w = ew[mp * NEDGES + e];
    unsigned long long v = (1ULL << 52) | (unsigned long long)(w * 1099511627776.0f); // 2^40
    atomicAdd(&degcnt[mp * NNODES + c], v);
}

// ---------------- unpack degcnt -> dinv, cnt; fused scan stage 1 ----------------
__global__ __launch_bounds__(256) void unpack_kernel(const unsigned long long* __restrict__ degcnt,
                                                     float* __restrict__ dinv,
                                                     int* __restrict__ cnt,
                                                     int* __restrict__ blockSums) {
    int t = threadIdx.x, b = blockIdx.x;
    int i4 = b * 256 + t;
    int s = 0;
    if (i4 < NTOT / 4) {
        ulonglong2 v01 = ((const ulonglong2*)degcnt)[i4 * 2];
        ulonglong2 v23 = ((const ulonglong2*)degcnt)[i4 * 2 + 1];
        unsigned long long vv[4] = {v01.x, v01.y, v23.x, v23.y};
        float dv[4]; int cv[4];
#pragma unroll
        for (int j = 0; j < 4; ++j) {
            unsigned long long v = vv[j];
            float deg = (float)(v & 0xFFFFFFFFFFFFFULL) * 0x1p-40f;
            dv[j] = (deg > 0.0f) ? rsqrtf(deg) : 0.0f;
            cv[j] = (int)(v >> 52);
            s += cv[j];
        }
        ((float4*)dinv)[i4] = make_float4(dv[0], dv[1], dv[2], dv[3]);
        ((int4*)cnt)[i4] = make_int4(cv[0], cv[1], cv[2], cv[3]);
    }
    for (int off = 32; off; off >>= 1) s += __shfl_down(s, off);
    __shared__ int red[4];
    if ((t & 63) == 0) red[t >> 6] = s;
    __syncthreads();
    if (t == 0) blockSums[b] = red[0] + red[1] + red[2] + red[3];
}

// ---------------- scan stage 2: exclusive scan of block sums (1 block) ----------------
__global__ __launch_bounds__(512) void scan2_kernel(const int* __restrict__ blockSums,
                                                    int* __restrict__ blockOffs,
                                                    int* __restrict__ offsetsEnd) {
    __shared__ int sh[512];
    int t = threadIdx.x;
    int v = (t < SCAN_BLOCKS) ? blockSums[t] : 0;
    sh[t] = v;
    __syncthreads();
    for (int d = 1; d < 512; d <<= 1) {
        int add = (t >= d) ? sh[t - d] : 0;
        __syncthreads();
        sh[t] += add;
        __syncthreads();
    }
    if (t < SCAN_BLOCKS) blockOffs[t] = sh[t] - v;
    if (t == 511) *offsetsEnd = sh[511];
}

// ---------------- scan stage 3: full offsets + cursor init ----------------
__global__ __launch_bounds__(256) void scan3_kernel(const int* __restrict__ cnt,
                                                    const int* __restrict__ blockOffs,
                                                    int* __restrict__ offsets,
                                                    int* __restrict__ cursor) {
    int t = threadIdx.x, b = blockIdx.x;
    int i4 = b * 256 + t;
    int4 v = (i4 < NTOT / 4) ? ((const int4*)cnt)[i4] : make_int4(0, 0, 0, 0);
    int s = v.x + v.y + v.z + v.w;
    __shared__ int sh[256];
    sh[t] = s;
    __syncthreads();
    for (int d = 1; d < 256; d <<= 1) {
        int add = (t >= d) ? sh[t - d] : 0;
        __syncthreads();
        sh[t] += add;
        __syncthreads();
    }
    int excl = sh[t] - s + blockOffs[b];
    if (i4 < NTOT / 4) {
        int4 o = make_int4(excl, excl + v.x, excl + v.x + v.y, excl + v.x + v.y + v.z);
        ((int4*)offsets)[i4] = o;
        ((int4*)cursor)[i4] = o;
    }
}

// ---------------- prep: W fp32 [mp][k][n] -> bf16 transposed wT [mp][n][k] ----------------
__global__ __launch_bounds__(256) void prep_w_kernel(const float* __restrict__ W,
                                                     unsigned short* __restrict__ wT) {
    for (int idx = threadIdx.x; idx < NMP * D * D; idx += 256) {
        int mp = idx >> 12;
        int rem = idx & 4095;
        int k = rem >> 6, n = rem & 63;
        wT[(mp * D + n) * D + k] = f2bf(W[idx]);
    }
}

// ---------------- MFMA GEMM: h[mp] = bf16(x) @ bf16(W[mp]), h stored bf16 ----------------
// one wave = 16 rows x 64 cols x 3 mp; A frags from global fp32 x (converted in regs),
// B frags straight from L1-resident wT. No LDS.
__global__ __launch_bounds__(256) void gemm_kernel(const float* __restrict__ x,
                                                   const unsigned short* __restrict__ wT,
                                                   unsigned short* __restrict__ h) {
    const int wave = threadIdx.x >> 6;
    const int lane = threadIdx.x & 63;
    const int rowbase = (blockIdx.x * 4 + wave) * 16;
    if (rowbase >= NNODES) return;
    const int m = lane & 15;
    const int q = lane >> 4;
    const int row = rowbase + m;
    const float4* xr = (const float4*)(x + (size_t)row * D);
    bf16x8 a[2];
#pragma unroll
    for (int kc = 0; kc < 2; ++kc) {
        float4 x0 = xr[kc * 8 + q * 2];
        float4 x1 = xr[kc * 8 + q * 2 + 1];
        a[kc][0] = f2bf(x0.x); a[kc][1] = f2bf(x0.y);
        a[kc][2] = f2bf(x0.z); a[kc][3] = f2bf(x0.w);
        a[kc][4] = f2bf(x1.x); a[kc][5] = f2bf(x1.y);
        a[kc][6] = f2bf(x1.z); a[kc][7] = f2bf(x1.w);
    }
#pragma unroll
    for (int mp = 0; mp < NMP; ++mp) {
#pragma unroll
        for (int nt = 0; nt < 4; ++nt) {
            int ncol = nt * 16 + m;
            const bf16x8* bp = (const bf16x8*)(wT + (size_t)(mp * D + ncol) * D);
            bf16x8 b0 = bp[q];       // k = q*8 .. +7
            bf16x8 b1 = bp[4 + q];   // k = 32 + q*8 .. +7
            floatx4 acc = {0.f, 0.f, 0.f, 0.f};
            acc = __builtin_amdgcn_mfma_f32_16x16x32_bf16(a[0], b0, acc, 0, 0, 0);
            acc = __builtin_amdgcn_mfma_f32_16x16x32_bf16(a[1], b1, acc, 0, 0, 0);
            unsigned short* hp = h + ((size_t)mp * NNODES + rowbase) * D + ncol;
#pragma unroll
            for (int r = 0; r < 4; ++r)
                hp[(q * 4 + r) * D] = f2bf(acc[r]);   // C/D: col=lane&15, row=q*4+r
        }
    }
}

// ---------------- placement: bucket {rflat, norm} by destination ----------------
__global__ __launch_bounds__(256) void place_kernel(const int* __restrict__ ei,
                                                    const float* __restrict__ ew,
                                                    const float* __restrict__ dinv,
                                                    int* __restrict__ cursor,
                                                    int2* __restrict__ pairs) {
    int e = blockIdx.x * 256 + threadIdx.x;
    int mp = blockIdx.y;
    if (e >= NEDGES) return;
    int r = ei[(mp * 2 + 0) * NEDGES + e];
    int c = ei[(mp * 2 + 1) * NEDGES + e];
    int rflat = mp * NNODES + r;
    int cflat = mp * NNODES + c;
    float norm = dinv[rflat] * ew[mp * NEDGES + e] * dinv[cflat];
    int pos = atomicAdd(&cursor[cflat], 1);
    pairs[pos] = make_int2(rflat, __float_as_int(norm));
}

// ---------------- gather: wave per node, 8 edges per iteration, bf16 h, fused ReLU ----------------
__global__ __launch_bounds__(256) void gather_kernel(const int* __restrict__ offsets,
                                                     const int2* __restrict__ pairs,
                                                     const unsigned short* __restrict__ h,
                                                     float* __restrict__ out) {
    int w = blockIdx.x * 4 + (threadIdx.x >> 6);
    if (w >= NTOT) return;
    int lane = threadIdx.x & 63;
    int g = lane & 7;    // edge subgroup
    int f = lane >> 3;   // feature chunk: features f*8 .. f*8+7
    int start = offsets[w], end = offsets[w + 1];
    float acc[8] = {0, 0, 0, 0, 0, 0, 0, 0};
    for (int p = start; p < end; p += 8) {
        int idx = p + g;
        int2 pr = (idx < end) ? pairs[idx] : make_int2(0, 0);
        float nrm = __int_as_float(pr.y);
        const uint4* hp = (const uint4*)(h + (size_t)pr.x * D);
        uint4 hv = hp[f];
        acc[0] += nrm * __uint_as_float(hv.x << 16);
        acc[1] += nrm * __uint_as_float(hv.x & 0xFFFF0000u);
        acc[2] += nrm * __uint_as_float(hv.y << 16);
        acc[3] += nrm * __uint_as_float(hv.y & 0xFFFF0000u);
        acc[4] += nrm * __uint_as_float(hv.z << 16);
        acc[5] += nrm * __uint_as_float(hv.z & 0xFFFF0000u);
        acc[6] += nrm * __uint_as_float(hv.w << 16);
        acc[7] += nrm * __uint_as_float(hv.w & 0xFFFF0000u);
    }
#pragma unroll
    for (int j = 0; j < 8; ++j) {
        acc[j] += __shfl_xor(acc[j], 1);
        acc[j] += __shfl_xor(acc[j], 2);
        acc[j] += __shfl_xor(acc[j], 4);
    }
    int k = lane & 7;   // lane l holds feature (l>>3)*8 + j in acc[j]; wants acc[l&7]
    float b0 = (k & 1) ? acc[1] : acc[0];
    float b1 = (k & 1) ? acc[3] : acc[2];
    float b2 = (k & 1) ? acc[5] : acc[4];
    float b3 = (k & 1) ? acc[7] : acc[6];
    float c0 = (k & 2) ? b1 : b0;
    float c1 = (k & 2) ? b3 : b2;
    float v  = (k & 4) ? c1 : c0;
    out[(size_t)w * D + lane] = fmaxf(v, 0.0f);
}

extern "C" void kernel_launch(void* const* d_in, const int* in_sizes, int n_in,
                              void* d_out, int out_size, void* d_ws, size_t ws_size,
                              hipStream_t stream) {
    const float* x  = (const float*)d_in[0];   // [N, 64]
    const float* W  = (const float*)d_in[1];   // [3, 64, 64]
    const int*   ei = (const int*)d_in[2];     // [3, 2, E]
    const float* ew = (const float*)d_in[3];   // [3, E]
    float* out = (float*)d_out;                // [3, N, 64]

    char* ws = (char*)d_ws;                                       // byte offsets, 16B-aligned
    unsigned long long* degcnt = (unsigned long long*)(ws + 0);   // 2,400,000 B
    float* dinv       = (float*)(ws + 2400000);                   // 1,200,000
    int*   cnt        = (int*)  (ws + 3600000);                   // 1,200,000
    int*   offsets    = (int*)  (ws + 4800000);                   // 1,200,004
    int*   cursor     = (int*)  (ws + 6000064);                   // 1,200,000
    int*   blockSums  = (int*)  (ws + 7200064);                   // 1,172
    int*   blockOffs  = (int*)  (ws + 7201280);                   // 1,172
    unsigned short* wT = (unsigned short*)(ws + 7202560);         // 24,576
    int2*  pairs      = (int2*) (ws + 7227392);                   // 24,000,000
    unsigned short* h = (unsigned short*)(ws + 31227392);         // 38,400,000

    hipMemsetAsync(degcnt, 0, 2400000, stream);

    dim3 egrid((NEDGES + 255) / 256, NMP);
    deg_cnt_kernel<<<egrid, 256, 0, stream>>>(ei, ew, degcnt);
    unpack_kernel<<<SCAN_BLOCKS, 256, 0, stream>>>(degcnt, dinv, cnt, blockSums);
    scan2_kernel<<<1, 512, 0, stream>>>(blockSums, blockOffs, &offsets[NTOT]);
    scan3_kernel<<<SCAN_BLOCKS, 256, 0, stream>>>(cnt, blockOffs, offsets, cursor);
    prep_w_kernel<<<1, 256, 0, stream>>>(W, wT);
    gemm_kernel<<<(NNODES / 16 + 3) / 4, 256, 0, stream>>>(x, wT, h);
    place_kernel<<<egrid, 256, 0, stream>>>(ei, ew, dinv, cursor, pairs);
    gather_kernel<<<(NTOT + 3) / 4, 256, 0, stream>>>(offsets, pairs, h, out);
}